// Round 2
// baseline (101.800 us; speedup 1.0000x reference)
//
#include <hip/hip_runtime.h>

// Chamfer distance, B=8, N=M=4096, D=3, fp32.
//
// Pipeline (3 kernels, one stream):
//  1. pack:   both clouds -> float4 (x, y, z, |p|^2) in ws; zero out[0].
//  2. main:   1024 blocks = 2 dir x 8 batch x 16 query-tiles x 4 target-chunks.
//             Each thread owns one query, scans a 1024-target chunk with
//             e = t2 - 2*q.t (3 fma/target), 4 independent min accumulators,
//             writes partial min to ws.
//  3. reduce: min over 4 chunks, add |q|^2, clamp 0, scaled sum -> atomicAdd.
//
// min(max(q2+t2-2qt,0)) == max(q2 + min(t2-2qt), 0): max(.,0) and +q2 are
// monotone, so clamp/offset commute past the min.

#define CH_B     8
#define CH_NPTS  4096
#define CH_NQ    (2 * CH_B * CH_NPTS)   // 65536 query ids (both directions)
#define CH_NCH   4
#define CH_CHUNK (CH_NPTS / CH_NCH)     // 1024 targets per chunk

// ws layout: [0, 1MB) packed float4[2][8][4096]; [1MB, 2MB) partial float[4][65536]

__global__ __launch_bounds__(256) void chamfer_pack(
    const float* __restrict__ pred, const float* __restrict__ gt,
    float4* __restrict__ packed, float* __restrict__ out)
{
    const int i = blockIdx.x * 256 + threadIdx.x;      // 0..65535
    if (i == 0) out[0] = 0.0f;
    const int p = i & (CH_B * CH_NPTS - 1);
    const float* src = (i >> 15) ? gt : pred;
    const float x = src[p * 3 + 0];
    const float y = src[p * 3 + 1];
    const float z = src[p * 3 + 2];
    packed[i] = make_float4(x, y, z, fmaf(x, x, fmaf(y, y, z * z)));
}

__global__ __launch_bounds__(256) void chamfer_main(
    const float4* __restrict__ packed, float* __restrict__ partial)
{
    const int g     = blockIdx.x;
    const int chunk = g & 3;
    const int rest  = g >> 2;          // 0..255
    const int dir   = rest & 1;
    const int b     = (rest >> 1) & 7;
    const int tile  = rest >> 4;       // 0..15

    const float4* qcloud = packed + (size_t)dir * (CH_B * CH_NPTS) + b * CH_NPTS;
    const float4* tcloud = packed + (size_t)(dir ^ 1) * (CH_B * CH_NPTS) + b * CH_NPTS;

    const int q = tile * 256 + threadIdx.x;
    const float4 Q = qcloud[q];
    const float qx2 = -2.0f * Q.x;
    const float qy2 = -2.0f * Q.y;
    const float qz2 = -2.0f * Q.z;

    const float4* __restrict__ t = tcloud + chunk * CH_CHUNK;

    const float INF = 3.4028235e38f;
    float m0 = INF, m1 = INF, m2 = INF, m3 = INF;

    for (int j = 0; j < CH_CHUNK; j += 8) {
        float e[8];
        #pragma unroll
        for (int k = 0; k < 8; ++k) {
            const float4 T = t[j + k];   // wave-uniform address: broadcast load
            e[k] = fmaf(qx2, T.x, fmaf(qy2, T.y, fmaf(qz2, T.z, T.w)));
        }
        m0 = fminf(m0, fminf(e[0], e[1]));   // -> v_min3_f32
        m1 = fminf(m1, fminf(e[2], e[3]));
        m2 = fminf(m2, fminf(e[4], e[5]));
        m3 = fminf(m3, fminf(e[6], e[7]));
    }
    const float m = fminf(fminf(m0, m1), fminf(m2, m3));

    // global query id: dir*32768 + b*4096 + q  (== packed index of the query)
    partial[chunk * CH_NQ + dir * (CH_B * CH_NPTS) + b * CH_NPTS + q] = m;
}

__global__ __launch_bounds__(256) void chamfer_reduce(
    const float4* __restrict__ packed, const float* __restrict__ partial,
    float* __restrict__ out)
{
    __shared__ float wsum[4];
    const int i = blockIdx.x * 256 + threadIdx.x;      // query id 0..65535

    float m = fminf(fminf(partial[i],             partial[CH_NQ + i]),
                    fminf(partial[2 * CH_NQ + i], partial[3 * CH_NQ + i]));
    const float q2 = packed[i].w;                      // packed[i] IS query i's point
    const float d  = fmaxf(q2 + m, 0.0f);

    float s = d * (1.0f / (8.0f * 4096.0f));
    #pragma unroll
    for (int off = 32; off > 0; off >>= 1)
        s += __shfl_down(s, off);

    const int lane = threadIdx.x & 63;
    const int wid  = threadIdx.x >> 6;
    if (lane == 0) wsum[wid] = s;
    __syncthreads();
    if (threadIdx.x == 0)
        atomicAdd(out, wsum[0] + wsum[1] + wsum[2] + wsum[3]);
}

extern "C" void kernel_launch(void* const* d_in, const int* in_sizes, int n_in,
                              void* d_out, int out_size, void* d_ws, size_t ws_size,
                              hipStream_t stream) {
    const float* pred = (const float*)d_in[0];
    const float* gt   = (const float*)d_in[1];
    float* out        = (float*)d_out;

    float4* packed  = (float4*)d_ws;                              // 1 MB
    float*  partial = (float*)((char*)d_ws + (size_t)CH_NQ * 16); // 1 MB

    chamfer_pack  <<<CH_NQ / 256, 256, 0, stream>>>(pred, gt, packed, out);
    chamfer_main  <<<CH_NCH * 256, 256, 0, stream>>>(packed, partial);
    chamfer_reduce<<<CH_NQ / 256, 256, 0, stream>>>(packed, partial, out);
}